// Round 6
// baseline (1318.265 us; speedup 1.0000x reference)
//
#include <hip/hip_runtime.h>
#include <hip/hip_fp16.h>

#define F_IN 128
#define HDIM 64
#define NUM_GRAPHS 256
#define SCAN_BLK 256
#define SCAN_CHUNK 2048   // 256 threads x 8 elems

// --- degree histogram (int): deg[dst] += 1 per edge ---
__global__ void hist_kernel(const int* __restrict__ dst, int* __restrict__ deg, int e) {
    int i = blockIdx.x * blockDim.x + threadIdx.x;
    if (i < e) atomicAdd(&deg[dst[i]], 1);
}

// --- scan pass A: per-block sums of deg over SCAN_CHUNK elems ---
__global__ void scan_partial(const int* __restrict__ deg, int* __restrict__ partial, int n) {
    __shared__ int lds[SCAN_BLK];
    int b = blockIdx.x, t = threadIdx.x;
    int base = b * SCAN_CHUNK + t * 8;
    int s = 0;
#pragma unroll
    for (int j = 0; j < 8; ++j) { int idx = base + j; if (idx < n) s += deg[idx]; }
    lds[t] = s; __syncthreads();
    for (int off = SCAN_BLK / 2; off; off >>= 1) {
        if (t < off) lds[t] += lds[t + off];
        __syncthreads();
    }
    if (t == 0) partial[b] = lds[0];
}

// --- scan pass B: serial exclusive scan of block sums (nb ~ 49) ---
__global__ void scan_spine(int* __restrict__ partial, int nb, int* __restrict__ off_end) {
    if (threadIdx.x == 0 && blockIdx.x == 0) {
        int run = 0;
        for (int i = 0; i < nb; ++i) { int v = partial[i]; partial[i] = run; run += v; }
        off_end[0] = run;
    }
}

// --- scan pass C: final exclusive scan; writes off[], cursor[], dinv[] ---
__global__ void scan_final(const int* __restrict__ deg, const int* __restrict__ partial,
                           int* __restrict__ off, int* __restrict__ cursor,
                           float* __restrict__ dinv, int n) {
    __shared__ int lds[SCAN_BLK];
    int b = blockIdx.x, t = threadIdx.x;
    int base = b * SCAN_CHUNK + t * 8;
    int v[8]; int s = 0;
#pragma unroll
    for (int j = 0; j < 8; ++j) { int idx = base + j; v[j] = (idx < n) ? deg[idx] : 0; s += v[j]; }
    lds[t] = s; __syncthreads();
    for (int o = 1; o < SCAN_BLK; o <<= 1) {
        int y = (t >= o) ? lds[t - o] : 0;
        __syncthreads();
        if (t >= o) lds[t] += y;
        __syncthreads();
    }
    int run = partial[b] + lds[t] - s;
#pragma unroll
    for (int j = 0; j < 8; ++j) {
        int idx = base + j;
        if (idx < n) {
            off[idx] = run; cursor[idx] = run;
            dinv[idx] = rsqrtf((float)v[j] + 1.0f);   // +1 self-loop
        }
        run += v[j];
    }
}

// --- CSR fill: csr[cursor[dst]++] = src ---
__global__ void fill_kernel(const int* __restrict__ src, const int* __restrict__ dst,
                            int* __restrict__ cursor, int* __restrict__ csr, int e) {
    int i = blockIdx.x * blockDim.x + threadIdx.x;
    if (i < e) {
        int pos = atomicAdd(&cursor[dst[i]], 1);
        csr[pos] = src[i];
    }
}

// --- GEMM layer1: hws[n,64](fp16) = (x[n,128] @ W[128,64]) * dinv[row] ---
__global__ void gemm1_kernel(const float* __restrict__ A, const float* __restrict__ W,
                             const float* __restrict__ dinv, __half* __restrict__ out, int n) {
    __shared__ float Ws[F_IN * 64];
    for (int i = threadIdx.x; i < F_IN * 64; i += blockDim.x) Ws[i] = W[i];
    __syncthreads();
    int row  = blockIdx.x * (blockDim.x >> 6) + (threadIdx.x >> 6);
    int lane = threadIdx.x & 63;
    if (row >= n) return;
    const float4* ar = reinterpret_cast<const float4*>(A + (size_t)row * F_IN);
    float acc = 0.f;
#pragma unroll
    for (int k4 = 0; k4 < F_IN / 4; ++k4) {
        float4 av = ar[k4];
        acc = fmaf(av.x, Ws[(k4 * 4 + 0) * 64 + lane], acc);
        acc = fmaf(av.y, Ws[(k4 * 4 + 1) * 64 + lane], acc);
        acc = fmaf(av.z, Ws[(k4 * 4 + 2) * 64 + lane], acc);
        acc = fmaf(av.w, Ws[(k4 * 4 + 3) * 64 + lane], acc);
    }
    out[(size_t)row * 64 + lane] = __float2half(acc * dinv[row]);
}

// --- GEMM layer2: hws[n,64](fp16) = (h1[n,64](fp16) @ W[64,64]) * dinv[row] ---
__global__ void gemm2_kernel(const __half* __restrict__ A, const float* __restrict__ W,
                             const float* __restrict__ dinv, __half* __restrict__ out, int n) {
    __shared__ float Ws[HDIM * 64];
    for (int i = threadIdx.x; i < HDIM * 64; i += blockDim.x) Ws[i] = W[i];
    __syncthreads();
    int row  = blockIdx.x * (blockDim.x >> 6) + (threadIdx.x >> 6);
    int lane = threadIdx.x & 63;
    if (row >= n) return;
    const __half2* ar = reinterpret_cast<const __half2*>(A + (size_t)row * HDIM);
    float acc = 0.f;
#pragma unroll
    for (int k2 = 0; k2 < HDIM / 2; ++k2) {
        float2 av = __half22float2(ar[k2]);
        acc = fmaf(av.x, Ws[(k2 * 2 + 0) * 64 + lane], acc);
        acc = fmaf(av.y, Ws[(k2 * 2 + 1) * 64 + lane], acc);
    }
    out[(size_t)row * 64 + lane] = __float2half(acc * dinv[row]);
}

// --- gather: one wave per dst node; half-wave = edge slot, lane&31 = feature pair ---
// 8 chains x 2 half-waves = 16 fp16 rows (128B) in flight per wave.
template<bool POOL>
__global__ void gather_kernel(const int* __restrict__ off, const int* __restrict__ csr,
                              const __half2* __restrict__ hws, const float* __restrict__ dinv,
                              const float* __restrict__ b, const int* __restrict__ batch,
                              __half* __restrict__ hout, float* __restrict__ pooled,
                              float* __restrict__ cnt, int n) {
    int d = blockIdx.x * (blockDim.x >> 6) + (threadIdx.x >> 6);
    int lane = threadIdx.x & 63;
    if (d >= n) return;
    int half_id = lane >> 5;     // which edge of the pair
    int col = lane & 31;         // feature pair index (features 2col, 2col+1)
    int beg = off[d], end = off[d + 1];
    float2 acc[8];
#pragma unroll
    for (int j = 0; j < 8; ++j) { acc[j].x = 0.f; acc[j].y = 0.f; }

    for (int base = beg; base < end; base += 64) {
        int m = end - base; if (m > 64) m = 64;
        int myidx = (lane < m) ? csr[base + lane] : 0;
        int i = 0;
        for (; i + 16 <= m; i += 16) {          // 16 edges per iter, all-static acc idx
#pragma unroll
            for (int j = 0; j < 8; ++j) {
                int s = __shfl(myidx, i + 2 * j + half_id);
                float2 f = __half22float2(hws[(size_t)s * 32 + col]);
                acc[j].x += f.x; acc[j].y += f.y;
            }
        }
        for (; i < m; i += 4) {                 // tail: 4 edges per iter, 2 static chains
#pragma unroll
            for (int j = 0; j < 2; ++j) {
                int e2 = i + 2 * j + half_id;
                int s = __shfl(myidx, (e2 < m) ? e2 : 0);
                float2 f = __half22float2(hws[(size_t)s * 32 + col]);
                if (e2 < m) { acc[j].x += f.x; acc[j].y += f.y; }
            }
        }
    }
    float2 tot;
    tot.x = ((acc[0].x + acc[1].x) + (acc[2].x + acc[3].x)) +
            ((acc[4].x + acc[5].x) + (acc[6].x + acc[7].x));
    tot.y = ((acc[0].y + acc[1].y) + (acc[2].y + acc[3].y)) +
            ((acc[4].y + acc[5].y) + (acc[6].y + acc[7].y));
    // combine the two half-wave partial sums
    tot.x += __shfl_xor(tot.x, 32);
    tot.y += __shfl_xor(tot.y, 32);
    // self-loop term + bias + relu
    float2 self = __half22float2(hws[(size_t)d * 32 + col]);
    float di = dinv[d];
    float2 bb = reinterpret_cast<const float2*>(b)[col];
    float vx = fmaxf((tot.x + self.x) * di + bb.x, 0.f);
    float vy = fmaxf((tot.y + self.y) * di + bb.y, 0.f);
    float vsel = half_id ? vy : vx;
    int feat = 2 * col + half_id;
    if (POOL) {
        int g = batch[d];
        atomicAdd(&pooled[(size_t)g * 64 + feat], vsel);
        if (lane == 0) atomicAdd(&cnt[g], 1.0f);
    } else {
        hout[(size_t)d * 64 + feat] = __float2half(vsel);
    }
}

// --- per-graph head: out[g] = dot(pooled[g]/max(cnt,1), Wfc) + bfc ---
__global__ void final_kernel(const float* __restrict__ pooled, const float* __restrict__ cnt,
                             const float* __restrict__ Wfc, const float* __restrict__ bfc,
                             float* __restrict__ out) {
    int g = blockIdx.x;
    int lane = threadIdx.x;  // block = 64 = 1 wave
    float c = fmaxf(cnt[g], 1.0f);
    float v = (pooled[(size_t)g * 64 + lane] / c) * Wfc[lane];
#pragma unroll
    for (int off = 32; off; off >>= 1) v += __shfl_down(v, off);
    if (lane == 0) out[g] = v + bfc[0];
}

extern "C" void kernel_launch(void* const* d_in, const int* in_sizes, int n_in,
                              void* d_out, int out_size, void* d_ws, size_t ws_size,
                              hipStream_t stream) {
    const float* x    = (const float*)d_in[0];
    const int*   ei   = (const int*)d_in[1];
    const int*   batch= (const int*)d_in[2];
    const float* W1   = (const float*)d_in[3];
    const float* b1   = (const float*)d_in[4];
    const float* W2   = (const float*)d_in[5];
    const float* b2   = (const float*)d_in[6];
    const float* Wfc  = (const float*)d_in[7];
    const float* bfc  = (const float*)d_in[8];
    float* out = (float*)d_out;

    const int n = in_sizes[0] / F_IN;   // 100000
    const int e = in_sizes[1] / 2;      // 3200000
    const int* srcp = ei;
    const int* dstp = ei + e;

    size_t nAl = ((size_t)n + 256) & ~(size_t)255;
    int*    deg     = (int*)d_ws;                 // nAl ints
    int*    off     = deg + nAl;                  // nAl
    int*    cursor  = off + nAl;                  // nAl
    int*    partial = cursor + nAl;               // 256
    float*  dinv    = (float*)(partial + 256);    // nAl
    int*    csr     = (int*)(dinv + nAl);         // eAl
    size_t  eAl     = ((size_t)e + 255) & ~(size_t)255;
    __half* hws     = (__half*)(csr + eAl);       // n*64 halves
    __half* h1      = hws + (size_t)n * 64;       // n*64 halves
    float*  pooled  = (float*)(h1 + (size_t)n * 64);   // 256*64
    float*  cnt     = pooled + (size_t)NUM_GRAPHS * 64;

    const int nb = (n + SCAN_CHUNK - 1) / SCAN_CHUNK;

    // 1. CSR build
    hipMemsetAsync(deg, 0, (size_t)n * sizeof(int), stream);
    hist_kernel<<<(e + 255) / 256, 256, 0, stream>>>(dstp, deg, e);
    scan_partial<<<nb, SCAN_BLK, 0, stream>>>(deg, partial, n);
    scan_spine<<<1, 64, 0, stream>>>(partial, nb, &off[n]);
    scan_final<<<nb, SCAN_BLK, 0, stream>>>(deg, partial, off, cursor, dinv, n);
    fill_kernel<<<(e + 255) / 256, 256, 0, stream>>>(srcp, dstp, cursor, csr, e);

    // 2. layer 1
    gemm1_kernel<<<(n + 3) / 4, 256, 0, stream>>>(x, W1, dinv, hws, n);
    gather_kernel<false><<<(n + 3) / 4, 256, 0, stream>>>(off, csr, (const __half2*)hws,
                                                          dinv, b1, batch, h1,
                                                          nullptr, nullptr, n);

    // 3. layer 2
    gemm2_kernel<<<(n + 3) / 4, 256, 0, stream>>>(h1, W2, dinv, hws, n);
    hipMemsetAsync(pooled, 0, ((size_t)NUM_GRAPHS * 64 + NUM_GRAPHS) * sizeof(float), stream);
    gather_kernel<true><<<(n + 3) / 4, 256, 0, stream>>>(off, csr, (const __half2*)hws,
                                                         dinv, b2, batch, nullptr,
                                                         pooled, cnt, n);

    // 4. head
    final_kernel<<<NUM_GRAPHS, 64, 0, stream>>>(pooled, cnt, Wfc, bfc, out);
}

// Round 10
// 1239.727 us; speedup vs baseline: 1.0634x; 1.0634x over previous
//
#include <hip/hip_runtime.h>
#include <hip/hip_fp16.h>

#define F_IN 128
#define HDIM 64
#define NUM_GRAPHS 256
#define SCAN_BLK 256
#define SCAN_CHUNK 2048   // 256 threads x 8 elems

// --- degree histogram (int): deg[dst] += 1 per edge ---
__global__ void hist_kernel(const int* __restrict__ dst, int* __restrict__ deg, int e) {
    int i = blockIdx.x * blockDim.x + threadIdx.x;
    if (i < e) atomicAdd(&deg[dst[i]], 1);
}

// --- scan pass A: per-block sums of deg over SCAN_CHUNK elems ---
__global__ void scan_partial(const int* __restrict__ deg, int* __restrict__ partial, int n) {
    __shared__ int lds[SCAN_BLK];
    int b = blockIdx.x, t = threadIdx.x;
    int base = b * SCAN_CHUNK + t * 8;
    int s = 0;
#pragma unroll
    for (int j = 0; j < 8; ++j) { int idx = base + j; if (idx < n) s += deg[idx]; }
    lds[t] = s; __syncthreads();
    for (int off = SCAN_BLK / 2; off; off >>= 1) {
        if (t < off) lds[t] += lds[t + off];
        __syncthreads();
    }
    if (t == 0) partial[b] = lds[0];
}

// --- scan pass B: serial exclusive scan of block sums (nb ~ 49) ---
__global__ void scan_spine(int* __restrict__ partial, int nb, int* __restrict__ off_end) {
    if (threadIdx.x == 0 && blockIdx.x == 0) {
        int run = 0;
        for (int i = 0; i < nb; ++i) { int v = partial[i]; partial[i] = run; run += v; }
        off_end[0] = run;
    }
}

// --- scan pass C: final exclusive scan; writes off[], cursor[], dinv[] ---
__global__ void scan_final(const int* __restrict__ deg, const int* __restrict__ partial,
                           int* __restrict__ off, int* __restrict__ cursor,
                           float* __restrict__ dinv, int n) {
    __shared__ int lds[SCAN_BLK];
    int b = blockIdx.x, t = threadIdx.x;
    int base = b * SCAN_CHUNK + t * 8;
    int v[8]; int s = 0;
#pragma unroll
    for (int j = 0; j < 8; ++j) { int idx = base + j; v[j] = (idx < n) ? deg[idx] : 0; s += v[j]; }
    lds[t] = s; __syncthreads();
    for (int o = 1; o < SCAN_BLK; o <<= 1) {
        int y = (t >= o) ? lds[t - o] : 0;
        __syncthreads();
        if (t >= o) lds[t] += y;
        __syncthreads();
    }
    int run = partial[b] + lds[t] - s;
#pragma unroll
    for (int j = 0; j < 8; ++j) {
        int idx = base + j;
        if (idx < n) {
            off[idx] = run; cursor[idx] = run;
            dinv[idx] = rsqrtf((float)v[j] + 1.0f);   // +1 self-loop
        }
        run += v[j];
    }
}

// --- CSR fill: csr[cursor[dst]++] = src ---
__global__ void fill_kernel(const int* __restrict__ src, const int* __restrict__ dst,
                            int* __restrict__ cursor, int* __restrict__ csr, int e) {
    int i = blockIdx.x * blockDim.x + threadIdx.x;
    if (i < e) {
        int pos = atomicAdd(&cursor[dst[i]], 1);
        csr[pos] = src[i];
    }
}

// --- GEMM layer1: hws[n,64](fp16) = (x[n,128] @ W[128,64]) * dinv[row] ---
__global__ void gemm1_kernel(const float* __restrict__ A, const float* __restrict__ W,
                             const float* __restrict__ dinv, __half* __restrict__ out, int n) {
    __shared__ float Ws[F_IN * 64];
    for (int i = threadIdx.x; i < F_IN * 64; i += blockDim.x) Ws[i] = W[i];
    __syncthreads();
    int row  = blockIdx.x * (blockDim.x >> 6) + (threadIdx.x >> 6);
    int lane = threadIdx.x & 63;
    if (row >= n) return;
    const float4* ar = reinterpret_cast<const float4*>(A + (size_t)row * F_IN);
    float acc = 0.f;
#pragma unroll
    for (int k4 = 0; k4 < F_IN / 4; ++k4) {
        float4 av = ar[k4];
        acc = fmaf(av.x, Ws[(k4 * 4 + 0) * 64 + lane], acc);
        acc = fmaf(av.y, Ws[(k4 * 4 + 1) * 64 + lane], acc);
        acc = fmaf(av.z, Ws[(k4 * 4 + 2) * 64 + lane], acc);
        acc = fmaf(av.w, Ws[(k4 * 4 + 3) * 64 + lane], acc);
    }
    out[(size_t)row * 64 + lane] = __float2half(acc * dinv[row]);
}

// --- GEMM layer2: hws[n,64](fp16) = (h1[n,64](fp16) @ W[64,64]) * dinv[row] ---
__global__ void gemm2_kernel(const __half* __restrict__ A, const float* __restrict__ W,
                             const float* __restrict__ dinv, __half* __restrict__ out, int n) {
    __shared__ float Ws[HDIM * 64];
    for (int i = threadIdx.x; i < HDIM * 64; i += blockDim.x) Ws[i] = W[i];
    __syncthreads();
    int row  = blockIdx.x * (blockDim.x >> 6) + (threadIdx.x >> 6);
    int lane = threadIdx.x & 63;
    if (row >= n) return;
    const __half2* ar = reinterpret_cast<const __half2*>(A + (size_t)row * HDIM);
    float acc = 0.f;
#pragma unroll
    for (int k2 = 0; k2 < HDIM / 2; ++k2) {
        float2 av = __half22float2(ar[k2]);
        acc = fmaf(av.x, Ws[(k2 * 2 + 0) * 64 + lane], acc);
        acc = fmaf(av.y, Ws[(k2 * 2 + 1) * 64 + lane], acc);
    }
    out[(size_t)row * 64 + lane] = __float2half(acc * dinv[row]);
}

// --- gather: one wave per dst node, lane = feature (ushort load = one
// contiguous 128-B segment per instruction). 8 independent chains. ---
template<bool POOL>
__global__ void gather_kernel(const int* __restrict__ off, const int* __restrict__ csr,
                              const __half* __restrict__ hws, const float* __restrict__ dinv,
                              const float* __restrict__ b, const int* __restrict__ batch,
                              __half* __restrict__ hout, float* __restrict__ pooled,
                              float* __restrict__ cnt, int n) {
    int d = blockIdx.x * (blockDim.x >> 6) + (threadIdx.x >> 6);
    int lane = threadIdx.x & 63;
    if (d >= n) return;
    int beg = off[d], end = off[d + 1];
    float acc[8];
#pragma unroll
    for (int j = 0; j < 8; ++j) acc[j] = 0.f;

    for (int base = beg; base < end; base += 64) {
        int m = end - base; if (m > 64) m = 64;
        int myidx = (lane < m) ? csr[base + lane] : 0;
        int i = 0;
        for (; i + 8 <= m; i += 8) {
#pragma unroll
            for (int j = 0; j < 8; ++j) {
                int s = __shfl(myidx, i + j);
                acc[j] += __half2float(hws[(size_t)s * 64 + lane]);
            }
        }
        // tail < 8: fully unrolled, compile-time acc index, predicated add
#pragma unroll
        for (int j = 0; j < 7; ++j) {
            int idx = i + j;
            int s = __shfl(myidx, (idx < m) ? idx : 0);
            float f = __half2float(hws[(size_t)s * 64 + lane]);
            if (idx < m) acc[j] += f;
        }
    }
    float tot = ((acc[0] + acc[1]) + (acc[2] + acc[3])) +
                ((acc[4] + acc[5]) + (acc[6] + acc[7]));
    float v = (tot + __half2float(hws[(size_t)d * 64 + lane])) * dinv[d] + b[lane];
    v = fmaxf(v, 0.f);
    if (POOL) {
        int g = batch[d];
        atomicAdd(&pooled[(size_t)g * 64 + lane], v);
        if (lane == 0) atomicAdd(&cnt[g], 1.0f);
    } else {
        hout[(size_t)d * 64 + lane] = __float2half(v);
    }
}

// --- per-graph head: out[g] = dot(pooled[g]/max(cnt,1), Wfc) + bfc ---
__global__ void final_kernel(const float* __restrict__ pooled, const float* __restrict__ cnt,
                             const float* __restrict__ Wfc, const float* __restrict__ bfc,
                             float* __restrict__ out) {
    int g = blockIdx.x;
    int lane = threadIdx.x;  // block = 64 = 1 wave
    float c = fmaxf(cnt[g], 1.0f);
    float v = (pooled[(size_t)g * 64 + lane] / c) * Wfc[lane];
#pragma unroll
    for (int off = 32; off; off >>= 1) v += __shfl_down(v, off);
    if (lane == 0) out[g] = v + bfc[0];
}

extern "C" void kernel_launch(void* const* d_in, const int* in_sizes, int n_in,
                              void* d_out, int out_size, void* d_ws, size_t ws_size,
                              hipStream_t stream) {
    const float* x    = (const float*)d_in[0];
    const int*   ei   = (const int*)d_in[1];
    const int*   batch= (const int*)d_in[2];
    const float* W1   = (const float*)d_in[3];
    const float* b1   = (const float*)d_in[4];
    const float* W2   = (const float*)d_in[5];
    const float* b2   = (const float*)d_in[6];
    const float* Wfc  = (const float*)d_in[7];
    const float* bfc  = (const float*)d_in[8];
    float* out = (float*)d_out;

    const int n = in_sizes[0] / F_IN;   // 100000
    const int e = in_sizes[1] / 2;      // 3200000
    const int* srcp = ei;
    const int* dstp = ei + e;

    size_t nAl = ((size_t)n + 256) & ~(size_t)255;
    int*    deg     = (int*)d_ws;                 // nAl ints
    int*    off     = deg + nAl;                  // nAl
    int*    cursor  = off + nAl;                  // nAl
    int*    partial = cursor + nAl;               // 256
    float*  dinv    = (float*)(partial + 256);    // nAl
    int*    csr     = (int*)(dinv + nAl);         // eAl
    size_t  eAl     = ((size_t)e + 255) & ~(size_t)255;
    __half* hws     = (__half*)(csr + eAl);       // n*64 halves
    __half* h1      = hws + (size_t)n * 64;       // n*64 halves
    float*  pooled  = (float*)(h1 + (size_t)n * 64);   // 256*64
    float*  cnt     = pooled + (size_t)NUM_GRAPHS * 64;

    const int nb = (n + SCAN_CHUNK - 1) / SCAN_CHUNK;

    // 1. CSR build
    hipMemsetAsync(deg, 0, (size_t)n * sizeof(int), stream);
    hist_kernel<<<(e + 255) / 256, 256, 0, stream>>>(dstp, deg, e);
    scan_partial<<<nb, SCAN_BLK, 0, stream>>>(deg, partial, n);
    scan_spine<<<1, 64, 0, stream>>>(partial, nb, &off[n]);
    scan_final<<<nb, SCAN_BLK, 0, stream>>>(deg, partial, off, cursor, dinv, n);
    fill_kernel<<<(e + 255) / 256, 256, 0, stream>>>(srcp, dstp, cursor, csr, e);

    // 2. layer 1
    gemm1_kernel<<<(n + 3) / 4, 256, 0, stream>>>(x, W1, dinv, hws, n);
    gather_kernel<false><<<(n + 3) / 4, 256, 0, stream>>>(off, csr, hws, dinv, b1, batch,
                                                          h1, nullptr, nullptr, n);

    // 3. layer 2
    gemm2_kernel<<<(n + 3) / 4, 256, 0, stream>>>(h1, W2, dinv, hws, n);
    hipMemsetAsync(pooled, 0, ((size_t)NUM_GRAPHS * 64 + NUM_GRAPHS) * sizeof(float), stream);
    gather_kernel<true><<<(n + 3) / 4, 256, 0, stream>>>(off, csr, hws, dinv, b2, batch,
                                                         nullptr, pooled, cnt, n);

    // 4. head
    final_kernel<<<NUM_GRAPHS, 64, 0, stream>>>(pooled, cnt, Wfc, bfc, out);
}